// Round 10
// baseline (158.641 us; speedup 1.0000x reference)
//
#include <hip/hip_runtime.h>
#include <hip/hip_bf16.h>
#include <stdint.h>

typedef unsigned short u16;
typedef unsigned int u32;
typedef short bf16x8 __attribute__((ext_vector_type(8)));
typedef float f32x4 __attribute__((ext_vector_type(4)));
typedef float f32x16 __attribute__((ext_vector_type(16)));

#define K_DIM 512

__device__ __forceinline__ u16 f2bf(float f) {
  union { float f; u32 u; } v; v.f = f;
  return (u16)((v.u + 0x8000u) >> 16);
}
// packed f32x2 -> bf16x2 (v_cvt_pk_bf16_f32 on gfx950 via hip header; lo in low half)
__device__ __forceinline__ u32 pkcvt(float lo, float hi) {
  union { __hip_bfloat162 h; u32 u; } c;
  c.h = __float22bfloat162_rn(float2{lo, hi});
  return c.u;
}
// async global->LDS DMA, 16B per lane; LDS dest must be wave-uniform base + lane*16
__device__ __forceinline__ void gl_lds16(const u16* g, u16* l) {
  __builtin_amdgcn_global_load_lds((const __attribute__((address_space(1))) void*)g,
                                   (__attribute__((address_space(3))) void*)l, 16, 0, 0);
}

// ---------------- kernel 0: fp32 -> bf16 conversions ----------------
__global__ void cvt_kernel(const float* __restrict__ x1, const float* __restrict__ x2,
                           const float* __restrict__ qkvw, const float* __restrict__ outw,
                           u16* __restrict__ xb, u16* __restrict__ wqkv, u16* __restrict__ wout) {
  int tid = blockIdx.x * 256 + threadIdx.x;
  const float4* src; u16* dst; int idx = tid;
  if (idx < 524288)        { src = (const float4*)x1;   dst = xb; }
  else if (idx < 1048576)  { src = (const float4*)x2;   dst = xb + 2097152; idx -= 524288; }
  else if (idx < 1245184)  { src = (const float4*)qkvw; dst = wqkv;         idx -= 1048576; }
  else                     { src = (const float4*)outw; dst = wout;         idx -= 1245184; }
  float4 v = src[idx];
  *(uint2*)&dst[idx * 4] = make_uint2(pkcvt(v.x, v.y), pkcvt(v.z, v.w));
}

#define LDA 32  // UNPADDED: required by global_load_lds lane*16 layout; b128 frag reads are 8 dw/bank

// ---------------- kernel 1: QKV GEMM (C^T, global_load_lds staging) + scatter epilogue ----------------
// f = h*192 + s*64 + d. q scaled by (1/8)*log2(e); q/k layout [in,b,h,l,d]; v transposed [in,b,h,d,l].
__global__ __launch_bounds__(256, 4) void qkv_gemm(
    const u16* __restrict__ A, const u16* __restrict__ W, const float* __restrict__ bias,
    u16* __restrict__ qb, u16* __restrict__ kb, u16* __restrict__ vtb) {
  __shared__ __align__(16) u16 As[128 * LDA];   // 8 KB
  __shared__ __align__(16) u16 Bs[128 * LDA];   // 8 KB
  const int t = threadIdx.x;
  const int m0 = blockIdx.x * 128, n0 = blockIdx.y * 128;
  const int lane = t & 63, l16 = lane & 15, quad = lane >> 4;
  const int w = t >> 6;
  const int wm = (w >> 1) * 64, wn = (w & 1) * 64;
  const int sr = t >> 2, sc = (t & 3) * 8;      // staging: row t>>2, col-seg (t&3)*8

  const u16* Ap = A + (size_t)(m0 + sr) * K_DIM + sc;
  const u16* Wp = W + (size_t)(n0 + sr) * K_DIM + sc;
  u16* AsT = &As[t * 8];        // (t>>2)*32 + (t&3)*8 == 8t: wave-uniform base + lane*16B
  u16* BsT = &Bs[t * 8];

  f32x4 acc[4][4];
#pragma unroll
  for (int i = 0; i < 4; ++i)
#pragma unroll
    for (int j = 0; j < 4; ++j) acc[i][j] = (f32x4){0.f, 0.f, 0.f, 0.f};

  for (int kt = 0; kt < 16; ++kt) {
    const int ko = kt * 32;
    gl_lds16(Ap + ko, AsT);
    gl_lds16(Ap + 64 * K_DIM + ko, AsT + 64 * LDA);
    gl_lds16(Wp + ko, BsT);
    gl_lds16(Wp + 64 * K_DIM + ko, BsT + 64 * LDA);
    __syncthreads();   // compiler drains vmcnt before barrier -> tile visible
    bf16x8 af[4], bfr[4];
#pragma unroll
    for (int mi = 0; mi < 4; ++mi)
      af[mi] = *(const bf16x8*)&As[(wm + mi * 16 + l16) * LDA + quad * 8];
#pragma unroll
    for (int ni = 0; ni < 4; ++ni)
      bfr[ni] = *(const bf16x8*)&Bs[(wn + ni * 16 + l16) * LDA + quad * 8];
    // SWAPPED operands: C^T -> row(quad,r)=f-offset, col(l16)=m-offset
#pragma unroll
    for (int mi = 0; mi < 4; ++mi)
#pragma unroll
      for (int ni = 0; ni < 4; ++ni)
        acc[mi][ni] = __builtin_amdgcn_mfma_f32_16x16x32_bf16(bfr[ni], af[mi], acc[mi][ni], 0, 0, 0);
    __syncthreads();   // readers done before next iter's DMA overwrites
  }

  const int fbase = n0 + wn;
  const int h = fbase / 192;
  const int s = (fbase - h * 192) >> 6;
  float4 bv[4];
#pragma unroll
  for (int ni = 0; ni < 4; ++ni)
    bv[ni] = *(const float4*)&bias[fbase + ni * 16 + quad * 4];
  const int bh = m0 >> 11;
  const int lbase = (m0 & 2047) + wm;

  if (s == 2) {
    u16* dst = vtb + (size_t)((bh * 8 + h) * 64) * 2048;
#pragma unroll
    for (int mi = 0; mi < 4; ++mi) {
      int l = lbase + mi * 16 + l16;
#pragma unroll
      for (int ni = 0; ni < 4; ++ni)
#pragma unroll
        for (int r = 0; r < 4; ++r)
          dst[(ni * 16 + quad * 4 + r) * 2048 + l] = f2bf(acc[mi][ni][r] + bv[ni][r]);
    }
  } else {
    u16* dst = (s == 0 ? qb : kb) + (size_t)((bh * 8 + h) * 2048) * 64;
    const float sc2 = (s == 0) ? 0.18033688011112042f : 1.0f;
#pragma unroll
    for (int mi = 0; mi < 4; ++mi) {
      int l = lbase + mi * 16 + l16;
#pragma unroll
      for (int ni = 0; ni < 4; ++ni) {
        float v0 = (acc[mi][ni][0] + bv[ni][0]) * sc2;
        float v1 = (acc[mi][ni][1] + bv[ni][1]) * sc2;
        float v2 = (acc[mi][ni][2] + bv[ni][2]) * sc2;
        float v3 = (acc[mi][ni][3] + bv[ni][3]) * sc2;
        *(uint2*)&dst[(size_t)l * 64 + ni * 16 + quad * 4] = make_uint2(pkcvt(v0, v1), pkcvt(v2, v3));
      }
    }
  }
}

// ---------------- kernel 2: flash cross-attention (S^T, 32x32x16 MFMA) ----------------
// grid 512: 128 q-rows/block, 4 waves x 32 q-rows; K-tiles of 64; XCD swizzle comb=bid&31.
// LDS: Ks 64x72 + VTs 64x72 + Ps 128x72 = 36864 B; padded LQ=72 verified 8 dw/bank.
#define LQ 72
#define LP 72

__global__ __launch_bounds__(256, 2) void attn_kernel(
    const u16* __restrict__ qb, const u16* __restrict__ kb, const u16* __restrict__ vtb,
    u16* __restrict__ attnb) {
  __shared__ __align__(16) u16 Ks[64 * LQ];    // [kcol][d]
  __shared__ __align__(16) u16 VTs[64 * LQ];   // [d][kcol]
  __shared__ __align__(16) u16 Ps[128 * LP];   // Q staging [qrow][d], then per-wave P [qrow][kcol]

  const int t = threadIdx.x;
  const int w = t >> 6, lane = t & 63, l32 = lane & 31, h2 = lane >> 5;
  const int bid = blockIdx.x;
  const int comb = bid & 31;        // XCD swizzle
  const int qt = bid >> 5;
  const int h = comb & 7, bb = (comb >> 3) & 1, pair = comb >> 4;
  const int in_q = pair, in_kv = pair ^ 1;

  const u16* Qg = qb + (size_t)((in_q * 2 + bb) * 8 + h) * 2048 * 64;
  const u16* Kg = kb + (size_t)((in_kv * 2 + bb) * 8 + h) * 2048 * 64;
  const u16* Vg = vtb + (size_t)((in_kv * 2 + bb) * 8 + h) * 64 * 2048;

#pragma unroll
  for (int u = 0; u < 4; ++u) {
    int idx = u * 256 + t;
    int row = idx >> 3, seg = (idx & 7) * 8;
    *(uint4*)&Ps[row * LP + seg] = *(const uint4*)(Qg + (qt * 128 + row) * 64 + seg);
  }
  const int srow = t >> 3, sseg = (t & 7) * 8;
  uint4 rk0 = *(const uint4*)(Kg + srow * 64 + sseg);
  uint4 rk1 = *(const uint4*)(Kg + (srow + 32) * 64 + sseg);
  uint4 rv0 = *(const uint4*)(Vg + srow * 2048 + sseg);
  uint4 rv1 = *(const uint4*)(Vg + (srow + 32) * 2048 + sseg);
  __syncthreads();

  bf16x8 qf[4];
#pragma unroll
  for (int ks = 0; ks < 4; ++ks)
    qf[ks] = *(const bf16x8*)&Ps[(w * 32 + l32) * LP + ks * 16 + h2 * 8];

  f32x16 oacc[2];
#pragma unroll
  for (int mi = 0; mi < 2; ++mi)
#pragma unroll
    for (int r = 0; r < 16; ++r) oacc[mi][r] = 0.f;
  float rs = 0.f;

  u16* Pw = &Ps[w * 32 * LP];

  for (int kt = 0; kt < 32; ++kt) {
    *(uint4*)&Ks[srow * LQ + sseg] = rk0;
    *(uint4*)&Ks[(srow + 32) * LQ + sseg] = rk1;
    *(uint4*)&VTs[srow * LQ + sseg] = rv0;
    *(uint4*)&VTs[(srow + 32) * LQ + sseg] = rv1;
    __syncthreads();
    if (kt < 31) {
      int ko = (kt + 1) * 64;
      rk0 = *(const uint4*)(Kg + (ko + srow) * 64 + sseg);
      rk1 = *(const uint4*)(Kg + (ko + srow + 32) * 64 + sseg);
      rv0 = *(const uint4*)(Vg + srow * 2048 + ko + sseg);
      rv1 = *(const uint4*)(Vg + (srow + 32) * 2048 + ko + sseg);
    }

    // S^T[kcol 64][qrow 32] = K (A) . Q (B)
    f32x16 sacc[2];
#pragma unroll
    for (int mi = 0; mi < 2; ++mi)
#pragma unroll
      for (int r = 0; r < 16; ++r) sacc[mi][r] = 0.f;
#pragma unroll
    for (int ks = 0; ks < 4; ++ks) {
      bf16x8 kfr0 = *(const bf16x8*)&Ks[(l32) * LQ + ks * 16 + h2 * 8];
      bf16x8 kfr1 = *(const bf16x8*)&Ks[(32 + l32) * LQ + ks * 16 + h2 * 8];
      sacc[0] = __builtin_amdgcn_mfma_f32_32x32x16_bf16(kfr0, qf[ks], sacc[0], 0, 0, 0);
      sacc[1] = __builtin_amdgcn_mfma_f32_32x32x16_bf16(kfr1, qf[ks], sacc[1], 0, 0, 0);
    }

    // p = exp2(s); reg-group rg = 4 consecutive kcols of qrow l32 -> b64 writes
#pragma unroll
    for (int mi = 0; mi < 2; ++mi)
#pragma unroll
      for (int rg = 0; rg < 4; ++rg) {
        float p0 = __builtin_amdgcn_exp2f(sacc[mi][rg * 4 + 0]);
        float p1 = __builtin_amdgcn_exp2f(sacc[mi][rg * 4 + 1]);
        float p2 = __builtin_amdgcn_exp2f(sacc[mi][rg * 4 + 2]);
        float p3 = __builtin_amdgcn_exp2f(sacc[mi][rg * 4 + 3]);
        rs += (p0 + p1) + (p2 + p3);
        *(uint2*)&Pw[l32 * LP + mi * 32 + rg * 8 + h2 * 4] = make_uint2(pkcvt(p0, p1), pkcvt(p2, p3));
      }

    // O^T[d 64][qrow 32] += V^T (A) . P (B)
#pragma unroll
    for (int ks = 0; ks < 4; ++ks) {
      bf16x8 pf = *(const bf16x8*)&Pw[l32 * LP + ks * 16 + h2 * 8];
      bf16x8 vf0 = *(const bf16x8*)&VTs[(l32) * LQ + ks * 16 + h2 * 8];
      bf16x8 vf1 = *(const bf16x8*)&VTs[(32 + l32) * LQ + ks * 16 + h2 * 8];
      oacc[0] = __builtin_amdgcn_mfma_f32_32x32x16_bf16(vf0, pf, oacc[0], 0, 0, 0);
      oacc[1] = __builtin_amdgcn_mfma_f32_32x32x16_bf16(vf1, pf, oacc[1], 0, 0, 0);
    }
    __syncthreads();
  }

  rs += __shfl_xor(rs, 32);
  const float inv = 1.0f / rs;
  const int row = in_q * 4096 + bb * 2048 + qt * 128 + w * 32 + l32;
#pragma unroll
  for (int mi = 0; mi < 2; ++mi)
#pragma unroll
    for (int rg = 0; rg < 4; ++rg) {
      float v0 = oacc[mi][rg * 4 + 0] * inv;
      float v1 = oacc[mi][rg * 4 + 1] * inv;
      float v2 = oacc[mi][rg * 4 + 2] * inv;
      float v3 = oacc[mi][rg * 4 + 3] * inv;
      *(uint2*)&attnb[(size_t)row * 512 + h * 64 + mi * 32 + rg * 8 + h2 * 4] =
          make_uint2(pkcvt(v0, v1), pkcvt(v2, v3));
    }
}

// ---------------- kernel 3: output projection (64x128 tiles, global_load_lds staging) ----------------
__global__ __launch_bounds__(256, 4) void out_gemm(
    const u16* __restrict__ A, const u16* __restrict__ W, const float* __restrict__ bias,
    float* __restrict__ out) {
  __shared__ __align__(16) u16 As[64 * LDA];    // 4 KB
  __shared__ __align__(16) u16 Bs[128 * LDA];   // 8 KB
  const int t = threadIdx.x;
  const int m0 = blockIdx.x * 64, n0 = blockIdx.y * 128;
  const int lane = t & 63, l16 = lane & 15, quad = lane >> 4;
  const int w = t >> 6;
  const int wm = (w & 1) * 32, wn = (w >> 1) * 64;
  const int sr = t >> 2, sc = (t & 3) * 8;

  const u16* Ap = A + (size_t)(m0 + sr) * K_DIM + sc;
  const u16* Wp = W + (size_t)(n0 + sr) * K_DIM + sc;
  u16* AsT = &As[t * 8];
  u16* BsT = &Bs[t * 8];

  f32x4 acc[2][4];
#pragma unroll
  for (int i = 0; i < 2; ++i)
#pragma unroll
    for (int j = 0; j < 4; ++j) acc[i][j] = (f32x4){0.f, 0.f, 0.f, 0.f};

  for (int kt = 0; kt < 16; ++kt) {
    const int ko = kt * 32;
    gl_lds16(Ap + ko, AsT);
    gl_lds16(Wp + ko, BsT);
    gl_lds16(Wp + 64 * K_DIM + ko, BsT + 64 * LDA);
    __syncthreads();
    bf16x8 af[2], bfr[4];
#pragma unroll
    for (int mi = 0; mi < 2; ++mi)
      af[mi] = *(const bf16x8*)&As[(wm + mi * 16 + l16) * LDA + quad * 8];
#pragma unroll
    for (int ni = 0; ni < 4; ++ni)
      bfr[ni] = *(const bf16x8*)&Bs[(wn + ni * 16 + l16) * LDA + quad * 8];
#pragma unroll
    for (int mi = 0; mi < 2; ++mi)
#pragma unroll
      for (int ni = 0; ni < 4; ++ni)
        acc[mi][ni] = __builtin_amdgcn_mfma_f32_16x16x32_bf16(af[mi], bfr[ni], acc[mi][ni], 0, 0, 0);
    __syncthreads();
  }

#pragma unroll
  for (int ni = 0; ni < 4; ++ni) {
    int f = n0 + wn + ni * 16 + l16;
    float bv = bias[f];
#pragma unroll
    for (int mi = 0; mi < 2; ++mi)
#pragma unroll
      for (int r = 0; r < 4; ++r) {
        int m = m0 + wm + mi * 16 + quad * 4 + r;
        out[(size_t)m * 512 + f] = acc[mi][ni][r] + bv;
      }
  }
}

// ---------------- launcher ----------------
extern "C" void kernel_launch(void* const* d_in, const int* in_sizes, int n_in,
                              void* d_out, int out_size, void* d_ws, size_t ws_size,
                              hipStream_t stream) {
  const float* x1   = (const float*)d_in[0];
  const float* x2   = (const float*)d_in[1];
  const float* qkvw = (const float*)d_in[2];
  const float* qkvb = (const float*)d_in[3];
  const float* outw = (const float*)d_in[4];
  const float* outb = (const float*)d_in[5];
  float* out = (float*)d_out;
  char* ws = (char*)d_ws;

  u16* xb    = (u16*)(ws + 0);          // [8192][512] bf16
  u16* wqkv  = (u16*)(ws + 8388608);    // [1536][512]
  u16* wout  = (u16*)(ws + 9961472);    // [512][512]
  u16* qb    = (u16*)(ws + 10485760);   // [2][2][8][2048][64]
  u16* kb    = (u16*)(ws + 18874368);   // [2][2][8][2048][64]
  u16* vtb   = (u16*)(ws + 27262976);   // [2][2][8][64][2048]
  u16* attnb = (u16*)(ws + 0);          // [8192][512]  (aliases xb)

  cvt_kernel<<<5120, 256, 0, stream>>>(x1, x2, qkvw, outw, xb, wqkv, wout);

  dim3 g1(64, 12);
  qkv_gemm<<<g1, 256, 0, stream>>>(xb, wqkv, qkvb, qb, kb, vtb);

  attn_kernel<<<512, 256, 0, stream>>>(qb, kb, vtb, attnb);

  dim3 g3(128, 4);
  out_gemm<<<g3, 256, 0, stream>>>(attnb, wout, outb, out);
}